// Round 3
// baseline (115.692 us; speedup 1.0000x reference)
//
#include <hip/hip_runtime.h>
#include <math.h>

#define EPSV 1e-5f

typedef float f4v __attribute__((ext_vector_type(4)));

__device__ __forceinline__ float waveReduceSum(float v) {
#pragma unroll
    for (int o = 32; o > 0; o >>= 1) v += __shfl_down(v, o, 64);
    return v;
}

// ---------------------------------------------------------------------------
// K1 (k_head): everything cls-dependent, one block per n (32 blocks x 512 thr).
//   K[c]  = elu(cls@wq.T + bq)+1          (threads 0..255)
//   Q[c]  = (elu(cls@wk.T + bk)+1)/16     (threads 256..511)
//   Kw[c] = K*ln_w ;  T1 = sum K*ln_b ;  T2[g] = sum_{c in g} Kw
//   R[o]  = sum_c conv_w[o,c]*Q[c]
__global__ void __launch_bounds__(512) k_head(
        const float* __restrict__ cls,
        const float* __restrict__ wq, const float* __restrict__ bq,
        const float* __restrict__ wk, const float* __restrict__ bk,
        const float* __restrict__ ln_w, const float* __restrict__ ln_b,
        const float* __restrict__ conv_w,
        float* __restrict__ Kw, float* __restrict__ T1,
        float* __restrict__ T2, float* __restrict__ R) {
    int n = blockIdx.x, t = threadIdx.x;
    __shared__ float clsS[512];
    __shared__ float qs[256];
    __shared__ float kwS[256];
    __shared__ float red[4];
    clsS[t] = cls[(size_t)n * 512 + t];
    __syncthreads();
    const float4* cp4 = (const float4*)clsS;
    if (t < 256) {
        const float4* wr = (const float4*)(wq + (size_t)t * 512);
        float acc = 0.f;
#pragma unroll 8
        for (int k = 0; k < 128; ++k) {
            float4 w4 = wr[k], c4 = cp4[k];
            acc += w4.x * c4.x + w4.y * c4.y + w4.z * c4.z + w4.w * c4.w;
        }
        float xk = acc + bq[t];
        float Kv = (xk > 0.f ? xk : expf(xk) - 1.f) + 1.f;
        float kw = Kv * ln_w[t];
        Kw[n * 256 + t] = kw;
        kwS[t] = kw;
        float r = waveReduceSum(Kv * ln_b[t]);
        if ((t & 63) == 0) red[t >> 6] = r;
    } else {
        int c = t - 256;
        const float4* wr = (const float4*)(wk + (size_t)c * 512);
        float acc = 0.f;
#pragma unroll 8
        for (int k = 0; k < 128; ++k) {
            float4 w4 = wr[k], c4 = cp4[k];
            acc += w4.x * c4.x + w4.y * c4.y + w4.z * c4.z + w4.w * c4.w;
        }
        float xq = acc + bk[c];
        qs[c] = ((xq > 0.f ? xq : expf(xq) - 1.f) + 1.f) * 0.0625f;
    }
    __syncthreads();
    if (t == 0) T1[n] = red[0] + red[1] + red[2] + red[3];
    if (t < 64) T2[n * 64 + t] = kwS[4 * t] + kwS[4 * t + 1] + kwS[4 * t + 2] + kwS[4 * t + 3];
    if (t < 256) {
        const float4* cw = (const float4*)(conv_w + (size_t)t * 256);
        const float4* q4 = (const float4*)qs;
        float acc = 0.f;
#pragma unroll 8
        for (int k = 0; k < 64; ++k) {
            float4 w4 = cw[k], v4 = q4[k];
            acc += w4.x * v4.x + w4.y * v4.y + w4.z * v4.z + w4.w * v4.w;
        }
        R[n * 256 + t] = acc;
    }
}

// ---------------------------------------------------------------------------
// K2 (pass1): single HBM read of X producing
//   W[n,g,p] = sum_{c in g} Kw[n,c]*X[n,c,p]   (33.5 MB, stays in L3)
//   Sp/S2p[block,g] = per-tile partial sum/sumsq of X over group channels
// grid 512 = n*16+tile; 512 threads (8 waves); wave w owns groups 8w..8w+7.
__global__ void __launch_bounds__(512) k_pass1(
        const float* __restrict__ X, const float* __restrict__ Kw,
        float* __restrict__ W, float* __restrict__ Sp, float* __restrict__ S2p) {
    int n = blockIdx.x >> 4, tile = blockIdx.x & 15;
    int wv = threadIdx.x >> 6, lane = threadIdx.x & 63;
    __shared__ float kws[256];
    if (threadIdx.x < 256) kws[threadIdx.x] = Kw[n * 256 + threadIdx.x];
    __syncthreads();
    int pix = tile * 256 + lane * 4;
    const float* xb = X + ((size_t)n * 256 << 12) + pix;
#pragma unroll
    for (int go = 0; go < 8; ++go) {
        int g = wv * 8 + go;
        int c0 = g * 4;
        float ax = 0.f, ay = 0.f, az = 0.f, aw = 0.f;
        float s = 0.f, s2 = 0.f;
#pragma unroll
        for (int j = 0; j < 4; ++j) {
            float4 v = *(const float4*)(xb + ((size_t)(c0 + j) << 12));
            float kv = kws[c0 + j];
            ax += kv * v.x; ay += kv * v.y; az += kv * v.z; aw += kv * v.w;
            s  += v.x + v.y + v.z + v.w;
            s2 += v.x * v.x + v.y * v.y + v.z * v.z + v.w * v.w;
        }
        float4 acc = {ax, ay, az, aw};
        *(float4*)(W + ((size_t)(n * 64 + g) << 12) + pix) = acc;
        s = waveReduceSum(s);
        s2 = waveReduceSum(s2);
        if (lane == 0) {
            Sp[blockIdx.x * 64 + g] = s;
            S2p[blockIdx.x * 64 + g] = s2;
        }
    }
}

// ---------------------------------------------------------------------------
// K3 (k_s): inlined stats (inv1, B) + s = sum_g inv_g*W_g + B + block moments.
// grid 128 = n*4+tile; 256 threads; thread handles one float4 (4 pixels).
__global__ void k_s(const float* __restrict__ W,
                    const float* __restrict__ Sp, const float* __restrict__ S2p,
                    const float* __restrict__ T1, const float* __restrict__ T2,
                    float* __restrict__ sbuf,
                    float* __restrict__ p1, float* __restrict__ p2) {
    int n = blockIdx.x >> 2, tile = blockIdx.x & 3;
    int t = threadIdx.x;
    __shared__ float ivs[64];
    __shared__ float Bsh;
    __shared__ float q1[4], q2[4];
    if (t < 64) {
        float S = 0.f, S2 = 0.f;
#pragma unroll
        for (int tl = 0; tl < 16; ++tl) {
            S  += Sp[(n * 16 + tl) * 64 + t];
            S2 += S2p[(n * 16 + tl) * 64 + t];
        }
        float mu = S * (1.f / 16384.f);
        float var = S2 * (1.f / 16384.f) - mu * mu;
        float iv = rsqrtf(var + EPSV);
        ivs[t] = iv;
        // B[n] = T1 - sum_g iv*mu*T2  (threads 0..63 are one wave)
        float r = waveReduceSum(iv * mu * T2[n * 64 + t]);
        if (t == 0) Bsh = T1[n] - r;
    }
    __syncthreads();
    int pix = tile * 1024 + t * 4;
    const float* wb = W + ((size_t)n * 64 << 12) + pix;
    float Bn = Bsh;
    float sx = Bn, sy = Bn, sz = Bn, sw = Bn;
#pragma unroll 8
    for (int g = 0; g < 64; ++g) {
        float4 v = *(const float4*)(wb + ((size_t)g << 12));
        float iv = ivs[g];
        sx += iv * v.x; sy += iv * v.y; sz += iv * v.z; sw += iv * v.w;
    }
    float4 s4 = {sx, sy, sz, sw};
    *(float4*)(sbuf + n * 4096 + pix) = s4;
    float r1 = waveReduceSum(sx + sy + sz + sw);
    float r2 = waveReduceSum(sx * sx + sy * sy + sz * sz + sw * sw);
    int lane = t & 63, wid = t >> 6;
    if (lane == 0) { q1[wid] = r1; q2[wid] = r2; }
    __syncthreads();
    if (t == 0) {
        p1[blockIdx.x] = q1[0] + q1[1] + q1[2] + q1[3];
        p2[blockIdx.x] = q2[0] + q2[1] + q2[2] + q2[3];
    }
}

// ---------------------------------------------------------------------------
// K4 (k_final): inlined alpha/beta; out = s*alpha + beta + X.
// grid 8192 = n*256+o (one (n,o) 64x64 plane per block); 256 threads x 4 float4.
__global__ void k_final(const float* __restrict__ X, const float* __restrict__ sbuf,
                        const float* __restrict__ p1, const float* __restrict__ p2,
                        const float* __restrict__ R, const float* __restrict__ conv_b,
                        const float* __restrict__ gn_w, const float* __restrict__ gn_b,
                        float* __restrict__ out) {
    int b = blockIdx.x;
    int n = b >> 8, o = b & 255;
    int t = threadIdx.x;
    // per-block (all threads redundantly): alpha, beta for this (n,o)
    float a1 = 0.f, a2 = 0.f;
#pragma unroll
    for (int i = 0; i < 4; ++i) { a1 += p1[n * 4 + i]; a2 += p2[n * 4 + i]; }
    float Ms1 = a1 * (1.f / 4096.f);
    float Ms2 = a2 * (1.f / 4096.f);
    int g = o >> 2;
    float mR = 0.f, mR2 = 0.f, mRb = 0.f, mb = 0.f, mb2 = 0.f;
#pragma unroll
    for (int j = 0; j < 4; ++j) {
        float r = R[n * 256 + g * 4 + j];
        float bb = conv_b[g * 4 + j];
        mR += r; mR2 += r * r; mRb += r * bb; mb += bb; mb2 += bb * bb;
    }
    mR *= 0.25f; mR2 *= 0.25f; mRb *= 0.25f; mb *= 0.25f; mb2 *= 0.25f;
    float mu = Ms1 * mR + mb;
    float var = Ms2 * mR2 + 2.f * Ms1 * mRb + mb2 - mu * mu;
    float iv = rsqrtf(var + EPSV);
    float alpha = R[n * 256 + o] * iv * gn_w[o];
    float beta = (conv_b[o] - mu) * iv * gn_w[o] + gn_b[o];

    const float4* xp = (const float4*)X + (size_t)b * 1024;
    const float4* sp = (const float4*)sbuf + (size_t)n * 1024;
    f4v* op = (f4v*)out + (size_t)b * 1024;
#pragma unroll
    for (int i = 0; i < 4; ++i) {
        int idx = i * 256 + t;
        float4 x = xp[idx];
        float4 s = sp[idx];
        f4v r;
        r.x = fmaf(s.x, alpha, beta) + x.x;
        r.y = fmaf(s.y, alpha, beta) + x.y;
        r.z = fmaf(s.z, alpha, beta) + x.z;
        r.w = fmaf(s.w, alpha, beta) + x.w;
        __builtin_nontemporal_store(r, op + idx);
    }
}

// ---------------------------------------------------------------------------
extern "C" void kernel_launch(void* const* d_in, const int* in_sizes, int n_in,
                              void* d_out, int out_size, void* d_ws, size_t ws_size,
                              hipStream_t stream) {
    const float* X      = (const float*)d_in[0];
    const float* cls    = (const float*)d_in[1];
    const float* ln_w   = (const float*)d_in[2];
    const float* ln_b   = (const float*)d_in[3];
    const float* wq     = (const float*)d_in[4];
    const float* bq     = (const float*)d_in[5];
    const float* wk     = (const float*)d_in[6];
    const float* bk     = (const float*)d_in[7];
    const float* conv_w = (const float*)d_in[8];
    const float* conv_b = (const float*)d_in[9];
    const float* gn_w   = (const float*)d_in[10];
    const float* gn_b   = (const float*)d_in[11];

    float* ws = (float*)d_ws;
    float* Kw   = ws;            // 8192
    float* T1   = ws + 8192;     // 32
    float* T2   = ws + 8256;     // 2048 (64B-aligned start)
    float* R    = ws + 10304;    // 8192
    float* Sp   = ws + 18496;    // 32768
    float* S2p  = ws + 51264;    // 32768
    float* p1   = ws + 84032;    // 128
    float* p2   = ws + 84160;    // 128
    float* sbuf = ws + 131072;   // 131072 (16B aligned)
    float* W    = ws + 262144;   // 8,388,608 (33.5 MB)

    k_head<<<32, 512, 0, stream>>>(cls, wq, bq, wk, bk, ln_w, ln_b, conv_w,
                                   Kw, T1, T2, R);
    k_pass1<<<512, 512, 0, stream>>>(X, Kw, W, Sp, S2p);
    k_s<<<128, 256, 0, stream>>>(W, Sp, S2p, T1, T2, sbuf, p1, p2);
    k_final<<<8192, 256, 0, stream>>>(X, sbuf, p1, p2, R, conv_b, gn_w, gn_b,
                                      (float*)d_out);
}

// Round 4
// 90.975 us; speedup vs baseline: 1.2717x; 1.2717x over previous
//
#include <hip/hip_runtime.h>
#include <math.h>

#define EPSV 1e-5f

typedef float f4v __attribute__((ext_vector_type(4)));

__device__ __forceinline__ float waveReduceSum(float v) {
#pragma unroll
    for (int o = 32; o > 0; o >>= 1) v += __shfl_down(v, o, 64);
    return v;
}

// ---------------------------------------------------------------------------
// K1: K[n,c] = elu(cls@wq.T + bq)+1 ; Q[n,c] = (elu(cls@wk.T + bk)+1)/16
//     Kw[n,c] = K * ln_w[c]
// one wave per (n,c); 2048 blocks x 256 threads (4 waves each).  [R1-proven]
__global__ void k_kq(const float* __restrict__ cls,
                     const float* __restrict__ wq, const float* __restrict__ bq,
                     const float* __restrict__ wk, const float* __restrict__ bk,
                     const float* __restrict__ ln_w,
                     float* __restrict__ Kb, float* __restrict__ Qb,
                     float* __restrict__ Kw) {
    int w = blockIdx.x * 4 + (threadIdx.x >> 6); // 0..8191
    int lane = threadIdx.x & 63;
    int n = w >> 8, c = w & 255;
    const float* cp = cls + (size_t)n * 512;
    const float* qp = wq + (size_t)c * 512;
    const float* kp = wk + (size_t)c * 512;
    float aK = 0.f, aQ = 0.f;
#pragma unroll
    for (int i = 0; i < 8; ++i) {
        int kk = lane + i * 64;
        float cv = cp[kk];
        aK += cv * qp[kk];
        aQ += cv * kp[kk];
    }
    aK = waveReduceSum(aK);
    aQ = waveReduceSum(aQ);
    if (lane == 0) {
        float xk = aK + bq[c];
        float xq = aQ + bk[c];
        float Kv = (xk > 0.f ? xk : expf(xk) - 1.f) + 1.f;
        float Qv = ((xq > 0.f ? xq : expf(xq) - 1.f) + 1.f) * 0.0625f;
        Kb[w] = Kv;
        Qb[w] = Qv;
        Kw[w] = Kv * ln_w[c];
    }
}

// ---------------------------------------------------------------------------
// K2 (pass1): single HBM read of X producing
//   W[n,g,p] = sum_{c in g} Kw[n,c]*X[n,c,p]   (33.5 MB, stays in L3)
//   Sp/S2p[block,g] = per-tile partial sum/sumsq of X over group channels
// grid 512 = n*16+tile; 512 threads (8 waves).  [R1-proven, untouched]
__global__ void __launch_bounds__(512) k_pass1(
        const float* __restrict__ X, const float* __restrict__ Kw,
        float* __restrict__ W, float* __restrict__ Sp, float* __restrict__ S2p) {
    int n = blockIdx.x >> 4, tile = blockIdx.x & 15;
    int wv = threadIdx.x >> 6, lane = threadIdx.x & 63;
    __shared__ float kws[256];
    if (threadIdx.x < 256) kws[threadIdx.x] = Kw[n * 256 + threadIdx.x];
    __syncthreads();
    int pix = tile * 256 + lane * 4;
    const float* xb = X + ((size_t)n * 256 << 12) + pix;
#pragma unroll
    for (int go = 0; go < 8; ++go) {
        int g = wv * 8 + go;
        int c0 = g * 4;
        float ax = 0.f, ay = 0.f, az = 0.f, aw = 0.f;
        float s = 0.f, s2 = 0.f;
#pragma unroll
        for (int j = 0; j < 4; ++j) {
            float4 v = *(const float4*)(xb + ((size_t)(c0 + j) << 12));
            float kv = kws[c0 + j];
            ax += kv * v.x; ay += kv * v.y; az += kv * v.z; aw += kv * v.w;
            s  += v.x + v.y + v.z + v.w;
            s2 += v.x * v.x + v.y * v.y + v.z * v.z + v.w * v.w;
        }
        float4 acc = {ax, ay, az, aw};
        *(float4*)(W + ((size_t)(n * 64 + g) << 12) + pix) = acc;
        s = waveReduceSum(s);
        s2 = waveReduceSum(s2);
        if (lane == 0) {
            Sp[blockIdx.x * 64 + g] = s;
            S2p[blockIdx.x * 64 + g] = s2;
        }
    }
}

// ---------------------------------------------------------------------------
// K3 (k_s): wave0 reduces Sp/S2p -> iv per group, and B[n] (inline, from
// Kb/Kw/ln_b); then all threads: s = sum_g iv_g*W_g + B; block moments.
// grid 128 = n*4+tile; 256 threads; thread handles one float4 (4 pixels).
__global__ void k_s(const float* __restrict__ W,
                    const float* __restrict__ Sp, const float* __restrict__ S2p,
                    const float* __restrict__ Kb, const float* __restrict__ Kw,
                    const float* __restrict__ ln_b,
                    float* __restrict__ sbuf,
                    float* __restrict__ p1, float* __restrict__ p2) {
    int n = blockIdx.x >> 2, tile = blockIdx.x & 3;
    int t = threadIdx.x;
    __shared__ float ivs[64];
    __shared__ float Bsh;
    __shared__ float q1[4], q2[4];
    if (t < 64) {
        float S = 0.f, S2 = 0.f;
#pragma unroll
        for (int tl = 0; tl < 16; ++tl) {
            S  += Sp[(n * 16 + tl) * 64 + t];
            S2 += S2p[(n * 16 + tl) * 64 + t];
        }
        float mu = S * (1.f / 16384.f);
        float var = S2 * (1.f / 16384.f) - mu * mu;
        float iv = rsqrtf(var + EPSV);
        ivs[t] = iv;
        // per-lane (g=t): sum_{c in g} Kb*ln_b  -  iv*mu*sum_{c in g} Kw
        float t1 = 0.f, t2 = 0.f;
#pragma unroll
        for (int j = 0; j < 4; ++j) {
            int c = t * 4 + j;
            t1 += Kb[n * 256 + c] * ln_b[c];
            t2 += Kw[n * 256 + c];
        }
        float r = waveReduceSum(t1 - iv * mu * t2);
        if (t == 0) Bsh = r;
    }
    __syncthreads();
    int pix = tile * 1024 + t * 4;
    const float* wb = W + ((size_t)n * 64 << 12) + pix;
    float Bn = Bsh;
    float sx = Bn, sy = Bn, sz = Bn, sw = Bn;
#pragma unroll 8
    for (int g = 0; g < 64; ++g) {
        float4 v = *(const float4*)(wb + ((size_t)g << 12));
        float iv = ivs[g];
        sx += iv * v.x; sy += iv * v.y; sz += iv * v.z; sw += iv * v.w;
    }
    float4 s4 = {sx, sy, sz, sw};
    *(float4*)(sbuf + n * 4096 + pix) = s4;
    float r1 = waveReduceSum(sx + sy + sz + sw);
    float r2 = waveReduceSum(sx * sx + sy * sy + sz * sz + sw * sw);
    int lane = t & 63, wid = t >> 6;
    if (lane == 0) { q1[wid] = r1; q2[wid] = r2; }
    __syncthreads();
    if (t == 0) {
        p1[blockIdx.x] = q1[0] + q1[1] + q1[2] + q1[3];
        p2[blockIdx.x] = q2[0] + q2[1] + q2[2] + q2[3];
    }
}

// ---------------------------------------------------------------------------
// K4 (k_ab): R = conv_w@Q (kept in LDS) + alpha/beta.  grid 32, 256 thr.
__global__ void k_ab(const float* __restrict__ p1, const float* __restrict__ p2,
                     const float* __restrict__ Qb, const float* __restrict__ conv_w,
                     const float* __restrict__ conv_b,
                     const float* __restrict__ gn_w, const float* __restrict__ gn_b,
                     float* __restrict__ alpha, float* __restrict__ beta) {
    int n = blockIdx.x, t = threadIdx.x;
    __shared__ float qs[256];
    __shared__ float rs[256];
    __shared__ float Ms1s, Ms2s;
    qs[t] = Qb[n * 256 + t];
    if (t == 0) {
        float a = 0.f, b = 0.f;
#pragma unroll
        for (int i = 0; i < 4; ++i) { a += p1[n * 4 + i]; b += p2[n * 4 + i]; }
        Ms1s = a * (1.f / 4096.f);
        Ms2s = b * (1.f / 4096.f);
    }
    __syncthreads();
    const float4* cw = (const float4*)(conv_w + (size_t)t * 256);
    const float4* q4 = (const float4*)qs;
    float acc = 0.f;
#pragma unroll 8
    for (int k = 0; k < 64; ++k) {
        float4 w4 = cw[k], v4 = q4[k];
        acc += w4.x * v4.x + w4.y * v4.y + w4.z * v4.z + w4.w * v4.w;
    }
    rs[t] = acc;
    __syncthreads();
    float Ms1 = Ms1s, Ms2 = Ms2s;
    int g = t >> 2;
    float mR = 0.f, mR2 = 0.f, mRb = 0.f, mb = 0.f, mb2 = 0.f;
#pragma unroll
    for (int j = 0; j < 4; ++j) {
        float r = rs[g * 4 + j];
        float bb = conv_b[g * 4 + j];
        mR += r; mR2 += r * r; mRb += r * bb; mb += bb; mb2 += bb * bb;
    }
    mR *= 0.25f; mR2 *= 0.25f; mRb *= 0.25f; mb *= 0.25f; mb2 *= 0.25f;
    float mu = Ms1 * mR + mb;
    float var = Ms2 * mR2 + 2.f * Ms1 * mRb + mb2 - mu * mu;
    float iv = rsqrtf(var + EPSV);
    alpha[n * 256 + t] = acc * iv * gn_w[t];
    beta[n * 256 + t] = (conv_b[t] - mu) * iv * gn_w[t] + gn_b[t];
}

// ---------------------------------------------------------------------------
// K5 (k_final): out = s*alpha + beta + X  (float4, NT store). [R1-proven]
// grid: 32768 blocks x 256 threads, flat.
__global__ void k_final(const float* __restrict__ X, const float* __restrict__ sbuf,
                        const float* __restrict__ alpha, const float* __restrict__ beta,
                        float* __restrict__ out) {
    size_t idx4 = (size_t)blockIdx.x * 256 + threadIdx.x;
    size_t e = idx4 * 4;
    int n = (int)(e >> 20);          // 256*4096 elems per n
    int rem = (int)(e & 1048575);
    int o = rem >> 12;
    int pix = rem & 4095;
    float4 x = ((const float4*)X)[idx4];
    float4 s = *(const float4*)(sbuf + n * 4096 + pix);
    float a = alpha[n * 256 + o], b = beta[n * 256 + o];
    f4v r;
    r.x = fmaf(s.x, a, b) + x.x;
    r.y = fmaf(s.y, a, b) + x.y;
    r.z = fmaf(s.z, a, b) + x.z;
    r.w = fmaf(s.w, a, b) + x.w;
    __builtin_nontemporal_store(r, (f4v*)out + idx4);
}

// ---------------------------------------------------------------------------
extern "C" void kernel_launch(void* const* d_in, const int* in_sizes, int n_in,
                              void* d_out, int out_size, void* d_ws, size_t ws_size,
                              hipStream_t stream) {
    const float* X      = (const float*)d_in[0];
    const float* cls    = (const float*)d_in[1];
    const float* ln_w   = (const float*)d_in[2];
    const float* ln_b   = (const float*)d_in[3];
    const float* wq     = (const float*)d_in[4];
    const float* bq     = (const float*)d_in[5];
    const float* wk     = (const float*)d_in[6];
    const float* bk     = (const float*)d_in[7];
    const float* conv_w = (const float*)d_in[8];
    const float* conv_b = (const float*)d_in[9];
    const float* gn_w   = (const float*)d_in[10];
    const float* gn_b   = (const float*)d_in[11];

    float* ws = (float*)d_ws;
    float* Kb    = ws;            // 8192
    float* Qb    = ws + 8192;     // 8192
    float* Kw    = ws + 16384;    // 8192
    float* Sp    = ws + 24576;    // 32768
    float* S2p   = ws + 57344;    // 32768
    float* p1    = ws + 90112;    // 128
    float* p2    = ws + 90240;    // 128
    float* alpha = ws + 90368;    // 8192
    float* beta  = ws + 98560;    // 8192
    float* sbuf  = ws + 131072;   // 131072 (16B aligned)
    float* W     = ws + 262144;   // 8,388,608 (33.5 MB)

    k_kq<<<2048, 256, 0, stream>>>(cls, wq, bq, wk, bk, ln_w, Kb, Qb, Kw);
    k_pass1<<<512, 512, 0, stream>>>(X, Kw, W, Sp, S2p);
    k_s<<<128, 256, 0, stream>>>(W, Sp, S2p, Kb, Kw, ln_b, sbuf, p1, p2);
    k_ab<<<32, 256, 0, stream>>>(p1, p2, Qb, conv_w, conv_b, gn_w, gn_b, alpha, beta);
    k_final<<<32768, 256, 0, stream>>>(X, sbuf, alpha, beta, (float*)d_out);
}